// Round 1
// baseline (3373.568 us; speedup 1.0000x reference)
//
#include <hip/hip_runtime.h>
#include <hip/hip_bf16.h>
#include <cmath>

// Problem constants
#define BB   8
#define CIN  8
#define TT   12
#define HH   128
#define WW   128
#define HID  32
#define CCOMB (CIN + HID)   // 40
#define HW   (HH * WW)      // 16384

// ---------------------------------------------------------------------------
// Kernel A: gates conv (40 -> 64 ch), fused sigmoid.
//   reset channels (0..31): write reset*h into rh (workspace)
//   update channels (32..63): write u into out slice t (temporary storage)
// Grid: (W/16, H/16, B*4). Block: (16,16). Each block: 16 output channels.
// ---------------------------------------------------------------------------
__global__ __launch_bounds__(256) void gates_kernel(
    const float* __restrict__ x,     // (B, CIN, T, H, W)
    const float* __restrict__ h,     // (B, HID, H, W)  running hidden state
    const float* __restrict__ Wg,    // (64, 40, 3, 3)
    const float* __restrict__ bg,    // (64)
    float* __restrict__ rh,          // (B, HID, H, W)  workspace: reset*h
    float* __restrict__ out,         // (B, HID, T, H, W) full output base
    int t)
{
    const int bx = blockIdx.x, by = blockIdx.y, bz = blockIdx.z;
    const int b   = bz >> 2;
    const int co0 = (bz & 3) * 16;
    const int tx = threadIdx.x, ty = threadIdx.y;
    const int tid = ty * 16 + tx;
    const int ox = bx * 16 + tx, oy = by * 16 + ty;
    const int x0 = bx * 16 - 1, y0 = by * 16 - 1;

    __shared__ float tile[8][18][18];

    float acc[16];
#pragma unroll
    for (int i = 0; i < 16; ++i) acc[i] = 0.f;

    for (int chunk = 0; chunk < 5; ++chunk) {
        __syncthreads();
        // stage 8 input channels (18x18 halo tiles)
        for (int idx = tid; idx < 8 * 18 * 18; idx += 256) {
            int c   = idx / 324;
            int rem = idx - c * 324;
            int yy  = rem / 18, xx = rem - yy * 18;
            int gy = y0 + yy, gx = x0 + xx;
            float v = 0.f;
            if ((unsigned)gy < (unsigned)HH && (unsigned)gx < (unsigned)WW) {
                int ci = chunk * 8 + c;
                if (ci < CIN)
                    v = x[((((size_t)b * CIN + ci) * TT + t)) * HW + gy * WW + gx];
                else
                    v = h[(((size_t)b * HID) + (ci - CIN)) * HW + gy * WW + gx];
            }
            tile[c][yy][xx] = v;
        }
        __syncthreads();

#pragma unroll
        for (int c = 0; c < 8; ++c) {
            float nb[9];
#pragma unroll
            for (int ky = 0; ky < 3; ++ky)
#pragma unroll
                for (int kx = 0; kx < 3; ++kx)
                    nb[ky * 3 + kx] = tile[c][ty + ky][tx + kx];
            const int ci = chunk * 8 + c;
            const float* wp = Wg + ((size_t)co0 * CCOMB + ci) * 9;  // wp[co*360 + k]
#pragma unroll
            for (int co = 0; co < 16; ++co) {
#pragma unroll
                for (int k = 0; k < 9; ++k)
                    acc[co] = fmaf(nb[k], wp[(size_t)co * (CCOMB * 9) + k], acc[co]);
            }
        }
    }

    // epilogue: sigmoid + route
    if (co0 < HID) {
        // reset gates -> rh = sigmoid(.)*h
#pragma unroll
        for (int co = 0; co < 16; ++co) {
            int c = co0 + co;
            float g = 1.f / (1.f + expf(-(acc[co] + bg[c])));
            size_t hidx = (((size_t)b * HID + c)) * HW + oy * WW + ox;
            rh[hidx] = g * h[hidx];
        }
    } else {
        // update gates -> stash in out slice t
#pragma unroll
        for (int co = 0; co < 16; ++co) {
            int cu = co0 - HID + co;
            float g = 1.f / (1.f + expf(-(acc[co] + bg[co0 + co])));
            size_t oidx = ((((size_t)b * HID + cu) * TT) + t) * (size_t)HW + oy * WW + ox;
            out[oidx] = g;
        }
    }
}

// ---------------------------------------------------------------------------
// Kernel B: candidate conv (40 -> 32 ch) on [x_t, reset*h], fused tanh + blend.
//   h_next = (1-u)*h + u*cand; write to out slice t and running h.
// Grid: (W/16, H/16, B*2). Block: (16,16).
// ---------------------------------------------------------------------------
__global__ __launch_bounds__(256) void cand_kernel(
    const float* __restrict__ x,     // (B, CIN, T, H, W)
    const float* __restrict__ rh,    // (B, HID, H, W)
    const float* __restrict__ Wc,    // (32, 40, 3, 3)
    const float* __restrict__ bc,    // (32)
    float* __restrict__ out,         // (B, HID, T, H, W)
    float* __restrict__ hlast,       // (B, HID, H, W)
    int t)
{
    const int bx = blockIdx.x, by = blockIdx.y, bz = blockIdx.z;
    const int b   = bz >> 1;
    const int co0 = (bz & 1) * 16;
    const int tx = threadIdx.x, ty = threadIdx.y;
    const int tid = ty * 16 + tx;
    const int ox = bx * 16 + tx, oy = by * 16 + ty;
    const int x0 = bx * 16 - 1, y0 = by * 16 - 1;

    __shared__ float tile[8][18][18];

    float acc[16];
#pragma unroll
    for (int i = 0; i < 16; ++i) acc[i] = 0.f;

    for (int chunk = 0; chunk < 5; ++chunk) {
        __syncthreads();
        for (int idx = tid; idx < 8 * 18 * 18; idx += 256) {
            int c   = idx / 324;
            int rem = idx - c * 324;
            int yy  = rem / 18, xx = rem - yy * 18;
            int gy = y0 + yy, gx = x0 + xx;
            float v = 0.f;
            if ((unsigned)gy < (unsigned)HH && (unsigned)gx < (unsigned)WW) {
                int ci = chunk * 8 + c;
                if (ci < CIN)
                    v = x[((((size_t)b * CIN + ci) * TT + t)) * HW + gy * WW + gx];
                else
                    v = rh[(((size_t)b * HID) + (ci - CIN)) * HW + gy * WW + gx];
            }
            tile[c][yy][xx] = v;
        }
        __syncthreads();

#pragma unroll
        for (int c = 0; c < 8; ++c) {
            float nb[9];
#pragma unroll
            for (int ky = 0; ky < 3; ++ky)
#pragma unroll
                for (int kx = 0; kx < 3; ++kx)
                    nb[ky * 3 + kx] = tile[c][ty + ky][tx + kx];
            const int ci = chunk * 8 + c;
            const float* wp = Wc + ((size_t)co0 * CCOMB + ci) * 9;
#pragma unroll
            for (int co = 0; co < 16; ++co) {
#pragma unroll
                for (int k = 0; k < 9; ++k)
                    acc[co] = fmaf(nb[k], wp[(size_t)co * (CCOMB * 9) + k], acc[co]);
            }
        }
    }

    // epilogue: tanh + GRU blend
#pragma unroll
    for (int co = 0; co < 16; ++co) {
        int c = co0 + co;
        float cand = tanhf(acc[co] + bc[c]);
        size_t oidx = ((((size_t)b * HID + c) * TT) + t) * (size_t)HW + oy * WW + ox;
        size_t hidx = (((size_t)b * HID + c)) * HW + oy * WW + ox;
        float u    = out[oidx];     // stashed update gate
        float hold = hlast[hidx];
        float hn = (1.f - u) * hold + u * cand;
        out[oidx]   = hn;
        hlast[hidx] = hn;
    }
}

extern "C" void kernel_launch(void* const* d_in, const int* in_sizes, int n_in,
                              void* d_out, int out_size, void* d_ws, size_t ws_size,
                              hipStream_t stream) {
    const float* x    = (const float*)d_in[0];
    const float* Wg   = (const float*)d_in[1];
    const float* bg   = (const float*)d_in[2];
    const float* Wc   = (const float*)d_in[3];
    const float* bc   = (const float*)d_in[4];

    float* out   = (float*)d_out;
    float* hlast = out + (size_t)BB * HID * TT * HW;   // h_last region of d_out
    float* rh    = (float*)d_ws;                       // 16 MB scratch: reset*h

    // h0 = 0
    hipMemsetAsync(hlast, 0, (size_t)BB * HID * HW * sizeof(float), stream);

    for (int t = 0; t < TT; ++t) {
        gates_kernel<<<dim3(WW / 16, HH / 16, BB * 4), dim3(16, 16), 0, stream>>>(
            x, hlast, Wg, bg, rh, out, t);
        cand_kernel<<<dim3(WW / 16, HH / 16, BB * 2), dim3(16, 16), 0, stream>>>(
            x, rh, Wc, bc, out, hlast, t);
    }
}

// Round 2
// 908.431 us; speedup vs baseline: 3.7136x; 3.7136x over previous
//
#include <hip/hip_runtime.h>
#include <hip/hip_bf16.h>
#include <cmath>

#define BB   8
#define CIN  8
#define TT   12
#define HH   128
#define WW   128
#define HID  32
#define CCOMB 40          // CIN + HID
#define HW   (HH * WW)

typedef __attribute__((ext_vector_type(8))) short short8;
typedef __attribute__((ext_vector_type(4))) float f32x4;

__device__ inline unsigned short f2bf(float f) {
    union { float f; unsigned u; } v; v.f = f;
    unsigned u = v.u;
    return (unsigned short)((u + 0x7FFFu + ((u >> 16) & 1u)) >> 16);
}

// A-fragment gather: weights in OIHW fp32 -> bf16 fragment for
// mfma_f32_16x16x32_bf16 with M = co, K = (ky*40 + ci) for fixed kx.
// K total = 120, padded to 128 (4 k-steps of 32); pad fragment = 0.
__device__ inline short8 gather_wfrag(const float* __restrict__ W,
                                      int co, int g, int kx, int ks) {
    int k0 = ks * 32 + g * 8;
    short8 f;
    if (k0 < 120) {
        int ky  = k0 / 40;
        int ci0 = k0 - ky * 40;     // 8-runs never cross a ky boundary (40%8==0)
#pragma unroll
        for (int i = 0; i < 8; ++i)
            f[i] = (short)f2bf(W[(((size_t)co * CCOMB + ci0 + i) * 3 + ky) * 3 + kx]);
    } else {
#pragma unroll
        for (int i = 0; i < 8; ++i) f[i] = 0;
    }
    return f;
}

// One-time weight repack into fragment order (coalesced dwordx4 loads later).
// Layout: [Gall(6 = 4 gates + 2 cand)][frag f=kx*4+ks (12)][lane (64)][8 bf16]
__global__ void pack_weights(const float* __restrict__ Wg,
                             const float* __restrict__ Wc,
                             unsigned short* __restrict__ pack) {
    int tid = blockIdx.x * blockDim.x + threadIdx.x;
    const int total = 6 * 12 * 64;
    if (tid >= total) return;
    int lane = tid & 63;
    int f    = (tid >> 6) % 12;
    int Gall = tid / (12 * 64);
    int kx = f >> 2, ks = f & 3;
    int g = lane >> 4;
    short8 v;
    if (Gall < 4) v = gather_wfrag(Wg, Gall * 16 + (lane & 15), g, kx, ks);
    else          v = gather_wfrag(Wc, (Gall - 4) * 16 + (lane & 15), g, kx, ks);
    *(short8*)&pack[(size_t)tid * 8] = v;
}

// ---------------------------------------------------------------------------
// Gates: conv(40->64) + sigmoid. Block: 256 thr = 4 waves (co-groups of 16),
// covers 4 rows x 16 cols of one image. reset*h -> rh, update -> out slice t.
// ---------------------------------------------------------------------------
__global__ __launch_bounds__(256) void gates_kernel(
    const float* __restrict__ x, const float* __restrict__ h,
    const float* __restrict__ Wg, const float* __restrict__ bg,
    const unsigned short* __restrict__ wpack,
    float* __restrict__ rh, float* __restrict__ out, int t)
{
    __shared__ __align__(16) unsigned short tile[6 * 18 * 40];
    const int b  = blockIdx.z;
    const int x0 = blockIdx.x * 16;
    const int y0 = blockIdx.y * 4;
    const int tid  = threadIdx.x;
    const int lane = tid & 63, wid = tid >> 6;
    const int m = lane & 15, g = lane >> 4;

    // stage input tile [pix(6x18)][ci(40)] as bf16
    for (int idx = tid; idx < 6 * 18 * 40; idx += 256) {
        int c = idx / 108, pix = idx - c * 108;
        int yy = pix / 18, xx = pix - yy * 18;
        int gy = y0 - 1 + yy, gx = x0 - 1 + xx;
        float v = 0.f;
        if ((unsigned)gy < (unsigned)HH && (unsigned)gx < (unsigned)WW) {
            if (c < CIN) v = x[(((size_t)b * CIN + c) * TT + t) * HW + gy * WW + gx];
            else         v = h[((size_t)b * HID + (c - CIN)) * HW + gy * WW + gx];
        }
        tile[pix * 40 + c] = f2bf(v);
    }

    // per-lane (ky, ci0) for each k-step
    int kyv[4], ci0v[4];
#pragma unroll
    for (int ks = 0; ks < 4; ++ks) {
        int k0 = ks * 32 + g * 8;
        kyv[ks] = 0; ci0v[ks] = 0;
        if (k0 < 120) { kyv[ks] = k0 / 40; ci0v[ks] = k0 - kyv[ks] * 40; }
    }

    // A-fragments (weights), register-resident: 12 x 4 VGPR
    short8 wf[12];
    if (wpack) {
#pragma unroll
        for (int f = 0; f < 12; ++f)
            wf[f] = *(const short8*)&wpack[(((size_t)wid * 12 + f) * 64 + lane) * 8];
    } else {
#pragma unroll
        for (int kx = 0; kx < 3; ++kx)
#pragma unroll
            for (int ks = 0; ks < 4; ++ks)
                wf[kx * 4 + ks] = gather_wfrag(Wg, wid * 16 + m, g, kx, ks);
    }

    __syncthreads();

    f32x4 acc[4] = {{0,0,0,0},{0,0,0,0},{0,0,0,0},{0,0,0,0}};
#pragma unroll
    for (int kx = 0; kx < 3; ++kx) {
#pragma unroll
        for (int ks = 0; ks < 4; ++ks) {
            int base = (kyv[ks] * 18 + (m + kx)) * 40 + ci0v[ks];
#pragma unroll
            for (int p = 0; p < 4; ++p) {
                short8 bfv = *(const short8*)(tile + base + p * 720);
                acc[p] = __builtin_amdgcn_mfma_f32_16x16x32_bf16(
                    wf[kx * 4 + ks], bfv, acc[p], 0, 0, 0);
            }
        }
    }

    // epilogue: D row = co = wid*16 + g*4 + r, col = pixel = m
    const int cobase = wid * 16 + g * 4;
    const int xo = x0 + m;
    float bias[4];
#pragma unroll
    for (int r = 0; r < 4; ++r) bias[r] = bg[cobase + r];

#pragma unroll
    for (int p = 0; p < 4; ++p) {
        int yo = y0 + p;
#pragma unroll
        for (int r = 0; r < 4; ++r) {
            int co = cobase + r;
            float gv = 1.f / (1.f + expf(-(acc[p][r] + bias[r])));
            if (wid < 2) {   // reset gates
                size_t hidx = ((size_t)b * HID + co) * HW + (size_t)yo * WW + xo;
                rh[hidx] = gv * h[hidx];
            } else {         // update gates -> stash in out slice t
                size_t oidx = (((size_t)b * HID + (co - 32)) * TT + t) * (size_t)HW
                            + (size_t)yo * WW + xo;
                out[oidx] = gv;
            }
        }
    }
}

// ---------------------------------------------------------------------------
// Candidate: conv(40->32) + tanh + GRU blend. Block: 256 thr = 4 waves
// (2 co-groups x 2 row-halves), covers 8 rows x 16 cols.
// ---------------------------------------------------------------------------
__global__ __launch_bounds__(256) void cand_kernel(
    const float* __restrict__ x, const float* __restrict__ rh,
    const float* __restrict__ Wc, const float* __restrict__ bc,
    const unsigned short* __restrict__ wpack,
    float* __restrict__ out, float* __restrict__ hlast, int t)
{
    __shared__ __align__(16) unsigned short tile[10 * 18 * 40];
    const int b  = blockIdx.z;
    const int x0 = blockIdx.x * 16;
    const int y0 = blockIdx.y * 8;
    const int tid  = threadIdx.x;
    const int lane = tid & 63, wid = tid >> 6;
    const int cg = wid & 1, yp = wid >> 1;
    const int m = lane & 15, g = lane >> 4;

    for (int idx = tid; idx < 10 * 18 * 40; idx += 256) {
        int c = idx / 180, pix = idx - c * 180;
        int yy = pix / 18, xx = pix - yy * 18;
        int gy = y0 - 1 + yy, gx = x0 - 1 + xx;
        float v = 0.f;
        if ((unsigned)gy < (unsigned)HH && (unsigned)gx < (unsigned)WW) {
            if (c < CIN) v = x[(((size_t)b * CIN + c) * TT + t) * HW + gy * WW + gx];
            else         v = rh[((size_t)b * HID + (c - CIN)) * HW + gy * WW + gx];
        }
        tile[pix * 40 + c] = f2bf(v);
    }

    int kyv[4], ci0v[4];
#pragma unroll
    for (int ks = 0; ks < 4; ++ks) {
        int k0 = ks * 32 + g * 8;
        kyv[ks] = 0; ci0v[ks] = 0;
        if (k0 < 120) { kyv[ks] = k0 / 40; ci0v[ks] = k0 - kyv[ks] * 40; }
    }

    short8 wf[12];
    if (wpack) {
        const unsigned short* wp = wpack + (size_t)4 * 12 * 64 * 8;  // cand region
#pragma unroll
        for (int f = 0; f < 12; ++f)
            wf[f] = *(const short8*)&wp[(((size_t)cg * 12 + f) * 64 + lane) * 8];
    } else {
#pragma unroll
        for (int kx = 0; kx < 3; ++kx)
#pragma unroll
            for (int ks = 0; ks < 4; ++ks)
                wf[kx * 4 + ks] = gather_wfrag(Wc, cg * 16 + m, g, kx, ks);
    }

    __syncthreads();

    f32x4 acc[4] = {{0,0,0,0},{0,0,0,0},{0,0,0,0},{0,0,0,0}};
#pragma unroll
    for (int kx = 0; kx < 3; ++kx) {
#pragma unroll
        for (int ks = 0; ks < 4; ++ks) {
            int base = ((kyv[ks] + yp * 4) * 18 + (m + kx)) * 40 + ci0v[ks];
#pragma unroll
            for (int p = 0; p < 4; ++p) {
                short8 bfv = *(const short8*)(tile + base + p * 720);
                acc[p] = __builtin_amdgcn_mfma_f32_16x16x32_bf16(
                    wf[kx * 4 + ks], bfv, acc[p], 0, 0, 0);
            }
        }
    }

    const int cobase = cg * 16 + g * 4;
    const int xo = x0 + m;
    float bias[4];
#pragma unroll
    for (int r = 0; r < 4; ++r) bias[r] = bc[cobase + r];

#pragma unroll
    for (int p = 0; p < 4; ++p) {
        int yo = y0 + yp * 4 + p;
#pragma unroll
        for (int r = 0; r < 4; ++r) {
            int co = cobase + r;
            float cand = tanhf(acc[p][r] + bias[r]);
            size_t oidx = (((size_t)b * HID + co) * TT + t) * (size_t)HW
                        + (size_t)yo * WW + xo;
            size_t hidx = ((size_t)b * HID + co) * HW + (size_t)yo * WW + xo;
            float u    = out[oidx];      // stashed update gate
            float hold = hlast[hidx];
            float hn = (1.f - u) * hold + u * cand;
            out[oidx]   = hn;
            hlast[hidx] = hn;
        }
    }
}

extern "C" void kernel_launch(void* const* d_in, const int* in_sizes, int n_in,
                              void* d_out, int out_size, void* d_ws, size_t ws_size,
                              hipStream_t stream) {
    const float* x  = (const float*)d_in[0];
    const float* Wg = (const float*)d_in[1];
    const float* bg = (const float*)d_in[2];
    const float* Wc = (const float*)d_in[3];
    const float* bc = (const float*)d_in[4];

    float* out   = (float*)d_out;
    float* hlast = out + (size_t)BB * HID * TT * HW;    // h_last region of d_out
    float* rh    = (float*)d_ws;                        // 16 MB: reset*h

    const size_t rh_bytes   = (size_t)BB * HID * HW * sizeof(float);
    const size_t pack_bytes = (size_t)6 * 12 * 64 * 8 * sizeof(unsigned short);
    unsigned short* wpack = nullptr;
    if (ws_size >= rh_bytes + pack_bytes) {
        wpack = (unsigned short*)((char*)d_ws + rh_bytes);
        pack_weights<<<(6 * 12 * 64 + 255) / 256, 256, 0, stream>>>(Wg, Wc, wpack);
    }

    hipMemsetAsync(hlast, 0, rh_bytes, stream);

    for (int t = 0; t < TT; ++t) {
        gates_kernel<<<dim3(WW / 16, HH / 4, BB), 256, 0, stream>>>(
            x, hlast, Wg, bg, wpack, rh, out, t);
        cand_kernel<<<dim3(WW / 16, HH / 8, BB), 256, 0, stream>>>(
            x, rh, Wc, bc, wpack, out, hlast, t);
    }
}

// Round 3
// 465.758 us; speedup vs baseline: 7.2432x; 1.9504x over previous
//
#include <hip/hip_runtime.h>
#include <hip/hip_bf16.h>
#include <hip/hip_fp16.h>
#include <cmath>

#define BB   8
#define CIN  8
#define TT   12
#define HH   128
#define WW   128
#define HID  32
#define CCOMB 40
#define HW   (HH * WW)
#define CPAD 44        // LDS channel stride (shorts): 88B row, conflict-free b64

typedef __attribute__((ext_vector_type(8))) short sv8;
typedef __attribute__((ext_vector_type(4))) short sv4;
typedef __attribute__((ext_vector_type(4))) float f32x4;
typedef unsigned short u16;

__device__ inline u16 f2bf(float f) {
    union { float f; unsigned u; } v; v.f = f;
    unsigned u = v.u;
    return (u16)((u + 0x7FFFu + ((u >> 16) & 1u)) >> 16);
}
__device__ inline float bf2f(u16 h) {
    union { unsigned u; float f; } v; v.u = ((unsigned)h) << 16; return v.f;
}

// ---------------------------------------------------------------------------
// Weight fragment gather (OIHW fp32 -> bf16 A-fragment), K=(ky*40+ci), pad 120->128
// ---------------------------------------------------------------------------
__device__ inline sv8 gather_wfrag(const float* __restrict__ W,
                                   int co, int g, int kx, int ks) {
    int k0 = ks * 32 + g * 8;
    sv8 f;
    if (k0 < 120) {
        int ky  = k0 / 40;
        int ci0 = k0 - ky * 40;
#pragma unroll
        for (int i = 0; i < 8; ++i)
            f[i] = (short)f2bf(W[(((size_t)co * CCOMB + ci0 + i) * 3 + ky) * 3 + kx]);
    } else {
#pragma unroll
        for (int i = 0; i < 8; ++i) f[i] = 0;
    }
    return f;
}

// pack layout: [Gall(6)][f(12)][lane(64)][8 bf16]
__global__ void pack_weights(const float* __restrict__ Wg,
                             const float* __restrict__ Wc,
                             u16* __restrict__ pack) {
    int tid = blockIdx.x * blockDim.x + threadIdx.x;
    if (tid >= 6 * 12 * 64) return;
    int lane = tid & 63;
    int f    = (tid >> 6) % 12;
    int Gall = tid / (12 * 64);
    int kx = f >> 2, ks = f & 3;
    int g = lane >> 4;
    sv8 v;
    if (Gall < 4) v = gather_wfrag(Wg, Gall * 16 + (lane & 15), g, kx, ks);
    else          v = gather_wfrag(Wc, (Gall - 4) * 16 + (lane & 15), g, kx, ks);
    *(sv8*)&pack[(size_t)tid * 8] = v;
}

// x (B,CIN,T,H,W) fp32 -> xbf (B,T,HW,8) bf16
__global__ __launch_bounds__(256) void x_to_bf16(const float* __restrict__ x,
                                                 u16* __restrict__ xbf) {
    int gid = blockIdx.x * 256 + threadIdx.x;
    if (gid >= BB * TT * HW) return;
    int p  = gid & (HW - 1);
    int bt = gid >> 14;
    int t = bt % TT, b = bt / TT;
    sv8 v;
#pragma unroll
    for (int c = 0; c < 8; ++c)
        v[c] = (short)f2bf(x[(((size_t)b * CIN + c) * TT + t) * HW + p]);
    *(sv8*)&xbf[(size_t)gid * 8] = v;
}

// ---------------------------------------------------------------------------
// Gates: conv(40->64)+sigmoid. 4 waves = 4 co-groups; 4 rows x 16 cols.
// reset -> rhbf (NHWC bf16), update -> ubf (fp16 NCHW plane).
// ---------------------------------------------------------------------------
__global__ __launch_bounds__(256) void gates_kernel(
    const u16* __restrict__ xbf, const float* __restrict__ x,
    const u16* __restrict__ hbf,
    const u16* __restrict__ wpack, const float* __restrict__ bg,
    u16* __restrict__ rhbf, u16* __restrict__ ubf, int t)
{
    __shared__ __align__(16) u16 tile[6 * 18 * CPAD];
    const int b = blockIdx.z, x0 = blockIdx.x * 16, y0 = blockIdx.y * 4;
    const int tid = threadIdx.x, lane = tid & 63, wid = tid >> 6;
    const int m = lane & 15, g = lane >> 4;

    // stage h channels (slots 8..40)
    for (int idx = tid; idx < 108 * 4; idx += 256) {
        int pix = idx >> 2, q = idx & 3;
        int yy = pix / 18, xx = pix - yy * 18;
        int gy = y0 - 1 + yy, gx = x0 - 1 + xx;
        sv8 v = {};
        if ((unsigned)gy < 128u && (unsigned)gx < 128u)
            v = *(const sv8*)&hbf[(((size_t)b * HW) + gy * WW + gx) * 32 + q * 8];
        *(sv4*)&tile[pix * CPAD + 8 + q * 8]     = __builtin_shufflevector(v, v, 0,1,2,3);
        *(sv4*)&tile[pix * CPAD + 8 + q * 8 + 4] = __builtin_shufflevector(v, v, 4,5,6,7);
    }
    // stage x channels (slots 0..8)
    if (xbf) {
        for (int idx = tid; idx < 108; idx += 256) {
            int yy = idx / 18, xx = idx - yy * 18;
            int gy = y0 - 1 + yy, gx = x0 - 1 + xx;
            sv8 v = {};
            if ((unsigned)gy < 128u && (unsigned)gx < 128u)
                v = *(const sv8*)&xbf[((((size_t)b * TT) + t) * HW + gy * WW + gx) * 8];
            *(sv4*)&tile[idx * CPAD]     = __builtin_shufflevector(v, v, 0,1,2,3);
            *(sv4*)&tile[idx * CPAD + 4] = __builtin_shufflevector(v, v, 4,5,6,7);
        }
    } else {
        for (int idx = tid; idx < 108 * 8; idx += 256) {
            int c = idx / 108, pix = idx - c * 108;
            int yy = pix / 18, xx = pix - yy * 18;
            int gy = y0 - 1 + yy, gx = x0 - 1 + xx;
            float v = 0.f;
            if ((unsigned)gy < 128u && (unsigned)gx < 128u)
                v = x[(((size_t)b * CIN + c) * TT + t) * HW + gy * WW + gx];
            tile[pix * CPAD + c] = f2bf(v);
        }
    }

    int kyv[4], ci0v[4];
#pragma unroll
    for (int ks = 0; ks < 4; ++ks) {
        int k0 = ks * 32 + g * 8;
        kyv[ks] = 0; ci0v[ks] = 0;
        if (k0 < 120) { kyv[ks] = k0 / 40; ci0v[ks] = k0 - kyv[ks] * 40; }
    }

    sv8 wf[12];
#pragma unroll
    for (int f = 0; f < 12; ++f)
        wf[f] = *(const sv8*)&wpack[(((size_t)wid * 12 + f) * 64 + lane) * 8];

    __syncthreads();

    f32x4 acc[4] = {{0,0,0,0},{0,0,0,0},{0,0,0,0},{0,0,0,0}};
#pragma unroll
    for (int kx = 0; kx < 3; ++kx) {
#pragma unroll
        for (int ks = 0; ks < 4; ++ks) {
            int base_pix = kyv[ks] * 18 + m + kx;
            int coff = ci0v[ks];
#pragma unroll
            for (int p = 0; p < 4; ++p) {
                const sv4* bp = (const sv4*)&tile[(base_pix + p * 18) * CPAD + coff];
                sv8 bv = __builtin_shufflevector(bp[0], bp[1], 0,1,2,3,4,5,6,7);
                acc[p] = __builtin_amdgcn_mfma_f32_16x16x32_bf16(wf[kx * 4 + ks], bv, acc[p], 0, 0, 0);
            }
        }
    }

    const int cobase = wid * 16 + g * 4;
    const int xo = x0 + m;
    float bias[4];
#pragma unroll
    for (int r = 0; r < 4; ++r) bias[r] = bg[cobase + r];

    if (wid < 2) {      // reset gates -> rh (bf16 NHWC); h read from LDS tile
#pragma unroll
        for (int p = 0; p < 4; ++p) {
            int yo = y0 + p;
#pragma unroll
            for (int r = 0; r < 4; ++r) {
                int co = cobase + r;
                float gv = 1.f / (1.f + expf(-(acc[p][r] + bias[r])));
                float hv = bf2f(tile[((p + 1) * 18 + m + 1) * CPAD + 8 + co]);
                rhbf[(((size_t)b * HW) + yo * WW + xo) * 32 + co] = f2bf(gv * hv);
            }
        }
    } else {            // update gates -> fp16 plane (NCHW, coalesced)
#pragma unroll
        for (int p = 0; p < 4; ++p) {
            int yo = y0 + p;
#pragma unroll
            for (int r = 0; r < 4; ++r) {
                int cu = cobase - 32 + r;
                float gv = 1.f / (1.f + expf(-(acc[p][r] + bias[r])));
                ubf[((size_t)b * HID + cu) * HW + yo * WW + xo] =
                    __half_as_ushort(__float2half(gv));
            }
        }
    }
}

// ---------------------------------------------------------------------------
// Candidate: conv(40->32)+tanh+blend. 4 waves = 2 co-groups x 2 row-halves;
// 8 rows x 16 cols. Writes out slice (fp32), hbf (bf16), hlast at t==11.
// ---------------------------------------------------------------------------
__global__ __launch_bounds__(256) void cand_kernel(
    const u16* __restrict__ xbf, const float* __restrict__ x,
    const u16* __restrict__ rhbf,
    const u16* __restrict__ wpack, const float* __restrict__ bc,
    const u16* __restrict__ ubf,
    float* __restrict__ out, u16* __restrict__ hbf,
    float* __restrict__ hlast, int t)
{
    __shared__ __align__(16) u16 tile[10 * 18 * CPAD];
    const int b = blockIdx.z, x0 = blockIdx.x * 16, y0 = blockIdx.y * 8;
    const int tid = threadIdx.x, lane = tid & 63, wid = tid >> 6;
    const int cg = wid & 1, yp = wid >> 1;
    const int m = lane & 15, g = lane >> 4;

    for (int idx = tid; idx < 180 * 4; idx += 256) {
        int pix = idx >> 2, q = idx & 3;
        int yy = pix / 18, xx = pix - yy * 18;
        int gy = y0 - 1 + yy, gx = x0 - 1 + xx;
        sv8 v = {};
        if ((unsigned)gy < 128u && (unsigned)gx < 128u)
            v = *(const sv8*)&rhbf[(((size_t)b * HW) + gy * WW + gx) * 32 + q * 8];
        *(sv4*)&tile[pix * CPAD + 8 + q * 8]     = __builtin_shufflevector(v, v, 0,1,2,3);
        *(sv4*)&tile[pix * CPAD + 8 + q * 8 + 4] = __builtin_shufflevector(v, v, 4,5,6,7);
    }
    if (xbf) {
        for (int idx = tid; idx < 180; idx += 256) {
            int yy = idx / 18, xx = idx - yy * 18;
            int gy = y0 - 1 + yy, gx = x0 - 1 + xx;
            sv8 v = {};
            if ((unsigned)gy < 128u && (unsigned)gx < 128u)
                v = *(const sv8*)&xbf[((((size_t)b * TT) + t) * HW + gy * WW + gx) * 8];
            *(sv4*)&tile[idx * CPAD]     = __builtin_shufflevector(v, v, 0,1,2,3);
            *(sv4*)&tile[idx * CPAD + 4] = __builtin_shufflevector(v, v, 4,5,6,7);
        }
    } else {
        for (int idx = tid; idx < 180 * 8; idx += 256) {
            int c = idx / 180, pix = idx - c * 180;
            int yy = pix / 18, xx = pix - yy * 18;
            int gy = y0 - 1 + yy, gx = x0 - 1 + xx;
            float v = 0.f;
            if ((unsigned)gy < 128u && (unsigned)gx < 128u)
                v = x[(((size_t)b * CIN + c) * TT + t) * HW + gy * WW + gx];
            tile[pix * CPAD + c] = f2bf(v);
        }
    }

    int kyv[4], ci0v[4];
#pragma unroll
    for (int ks = 0; ks < 4; ++ks) {
        int k0 = ks * 32 + g * 8;
        kyv[ks] = 0; ci0v[ks] = 0;
        if (k0 < 120) { kyv[ks] = k0 / 40; ci0v[ks] = k0 - kyv[ks] * 40; }
    }

    sv8 wf[12];
    {
        const u16* wp = wpack + (size_t)4 * 12 * 64 * 8;
#pragma unroll
        for (int f = 0; f < 12; ++f)
            wf[f] = *(const sv8*)&wp[(((size_t)cg * 12 + f) * 64 + lane) * 8];
    }

    __syncthreads();

    f32x4 acc[4] = {{0,0,0,0},{0,0,0,0},{0,0,0,0},{0,0,0,0}};
#pragma unroll
    for (int kx = 0; kx < 3; ++kx) {
#pragma unroll
        for (int ks = 0; ks < 4; ++ks) {
            int base_pix = (kyv[ks] + yp * 4) * 18 + m + kx;
            int coff = ci0v[ks];
#pragma unroll
            for (int p = 0; p < 4; ++p) {
                const sv4* bp = (const sv4*)&tile[(base_pix + p * 18) * CPAD + coff];
                sv8 bv = __builtin_shufflevector(bp[0], bp[1], 0,1,2,3,4,5,6,7);
                acc[p] = __builtin_amdgcn_mfma_f32_16x16x32_bf16(wf[kx * 4 + ks], bv, acc[p], 0, 0, 0);
            }
        }
    }

    const int cobase = cg * 16 + g * 4;
    const int xo = x0 + m;
    float bias[4];
#pragma unroll
    for (int r = 0; r < 4; ++r) bias[r] = bc[cobase + r];

#pragma unroll
    for (int p = 0; p < 4; ++p) {
        int yo = y0 + yp * 4 + p;
#pragma unroll
        for (int r = 0; r < 4; ++r) {
            int co = cobase + r;
            float cv = tanhf(acc[p][r] + bias[r]);
            size_t pixi = (size_t)b * HW + (size_t)yo * WW + xo;
            size_t plane = ((size_t)b * HID + co) * HW + (size_t)yo * WW + xo;
            float u    = __half2float(__ushort_as_half(ubf[plane]));
            float hold = bf2f(hbf[pixi * 32 + co]);
            float hn = (1.f - u) * hold + u * cv;
            out[((size_t)b * HID + co) * TT * HW + (size_t)t * HW + (size_t)yo * WW + xo] = hn;
            hbf[pixi * 32 + co] = f2bf(hn);
            if (t == TT - 1) hlast[plane] = hn;
        }
    }
}

extern "C" void kernel_launch(void* const* d_in, const int* in_sizes, int n_in,
                              void* d_out, int out_size, void* d_ws, size_t ws_size,
                              hipStream_t stream) {
    const float* x  = (const float*)d_in[0];
    const float* Wg = (const float*)d_in[1];
    const float* bg = (const float*)d_in[2];
    const float* Wc = (const float*)d_in[3];
    const float* bc = (const float*)d_in[4];

    float* out   = (float*)d_out;
    float* hlast = out + (size_t)BB * HID * TT * HW;

    const size_t PLANE = (size_t)BB * HW * 32 * sizeof(u16);   // 8 MB
    const size_t PACKB = (size_t)6 * 12 * 64 * 8 * sizeof(u16);
    const size_t XBFB  = (size_t)BB * TT * HW * 8 * sizeof(u16);

    char* ws = (char*)d_ws;
    u16* hbf   = (u16*)(ws);
    u16* rhbf  = (u16*)(ws + PLANE);
    u16* ubf   = (u16*)(ws + 2 * PLANE);
    u16* wpack = (u16*)(ws + 3 * PLANE);
    u16* xbf   = nullptr;
    if (ws_size >= 3 * PLANE + PACKB + XBFB + 256)
        xbf = (u16*)(ws + 3 * PLANE + PACKB);

    pack_weights<<<(6 * 12 * 64 + 255) / 256, 256, 0, stream>>>(Wg, Wc, wpack);
    if (xbf)
        x_to_bf16<<<(BB * TT * HW) / 256, 256, 0, stream>>>(x, xbf);
    hipMemsetAsync(hbf, 0, PLANE, stream);

    for (int t = 0; t < TT; ++t) {
        gates_kernel<<<dim3(WW / 16, HH / 4, BB), 256, 0, stream>>>(
            xbf, x, hbf, wpack, bg, rhbf, ubf, t);
        cand_kernel<<<dim3(WW / 16, HH / 8, BB), 256, 0, stream>>>(
            xbf, x, rhbf, wpack, bc, ubf, out, hbf, hlast, t);
    }
}